// Round 10
// baseline (228.279 us; speedup 1.0000x reference)
//
#include <hip/hip_runtime.h>
#include <hip/hip_bf16.h>

typedef __bf16 bf16_t;
typedef __bf16 bf16x4 __attribute__((ext_vector_type(4)));
typedef __bf16 bf16x8 __attribute__((ext_vector_type(8)));
typedef float f32x4 __attribute__((ext_vector_type(4)));

#define MFMA16(a, b, c) __builtin_amdgcn_mfma_f32_16x16x32_bf16((a), (b), (c), 0, 0, 0)

// async global->LDS, 16B per lane; dest = wave-uniform base + lane*16
__device__ __forceinline__ void gl16(const bf16_t* g, void* l) {
    __builtin_amdgcn_global_load_lds(
        (const __attribute__((address_space(1))) void*)g,
        (__attribute__((address_space(3))) void*)l, 16, 0, 0);
}

__device__ __forceinline__ float gelu_t(float u) {
    float t2 = fminf(u * (1.5957691216057308f + 0.07135481627f * u * u), 60.f);
    float e = __expf(t2);
    return u * e / (e + 1.f);
}

// Problem constants
// B=16, C=192, H=W=56, WIN=7, SHIFT=3, HEADS=6, DH=32, HID=768
// tokens M = 16*8*8*49 = 50176, windows = 1024

// ---------------- weight convert (4 weights -> contiguous bf16) ----------
__global__ __launch_bounds__(256) void k_cvt(const float* __restrict__ qkvw,
                                             const float* __restrict__ projw,
                                             const float* __restrict__ fc1w,
                                             const float* __restrict__ fc2w,
                                             bf16_t* __restrict__ dst)
{
    int i = blockIdx.x * 256 + threadIdx.x;
    if (i >= 442368) return;
    float v;
    if (i < 110592)      v = qkvw[i];
    else if (i < 147456) v = projw[i - 110592];
    else if (i < 294912) v = fc1w[i - 147456];
    else                 v = fc2w[i - 294912];
    dst[i] = (bf16_t)v;
}

// ---------------- LN1 + roll(-3) + window partition -> xw bf16 -----------
__global__ __launch_bounds__(1024) void k_ln1(const float* __restrict__ x,
                                              const float* __restrict__ gam,
                                              const float* __restrict__ bet,
                                              bf16_t* __restrict__ xw)
{
    __shared__ float tile[56][193];     // odd stride: conflict-free row reads
    __shared__ bf16_t obuf[56 * 192];   // row stride 384B = 24 int4
    const int bh = blockIdx.x;
    const int b = bh / 56, h = bh % 56;
    const int tid = threadIdx.x;

    // phase 1: x[b][:][h][:] -> tile[w][c] (float4 global loads)
    {
        const int g = tid >> 4, u = tid & 15;   // g: channel group 0..63
        const float* xb = x + (long)b * 602112 + (long)h * 56;
        if (u < 14) {
            #pragma unroll
            for (int k = 0; k < 3; ++k) {
                const int c = g + 64 * k;
                float4 v = *(const float4*)(xb + (long)c * 3136 + u * 4);
                tile[u * 4 + 0][c] = v.x;
                tile[u * 4 + 1][c] = v.y;
                tile[u * 4 + 2][c] = v.z;
                tile[u * 4 + 3][c] = v.w;
            }
        }
    }
    __syncthreads();

    // phase 2: LN per token (wave-parallel over w), bf16 -> obuf by rolled idx
    const int wave = tid >> 6, lane = tid & 63;
    const float g0 = gam[lane], g1 = gam[lane + 64], g2 = gam[lane + 128];
    const float b0 = bet[lane], b1 = bet[lane + 64], b2 = bet[lane + 128];
    for (int wp = wave; wp < 56; wp += 16) {
        float v0 = tile[wp][lane], v1 = tile[wp][lane + 64], v2 = tile[wp][lane + 128];
        float s = v0 + v1 + v2;
        float sq = v0 * v0 + v1 * v1 + v2 * v2;
        #pragma unroll
        for (int d = 1; d < 64; d <<= 1) { s += __shfl_xor(s, d); sq += __shfl_xor(sq, d); }
        float mean = s * (1.f / 192.f);
        float var  = sq * (1.f / 192.f) - mean * mean;
        float rs = rsqrtf(var + 1e-5f);
        const int wr = (wp + 53) % 56;
        bf16_t* o = obuf + wr * 192;
        o[lane]       = (bf16_t)((v0 - mean) * rs * g0 + b0);
        o[lane + 64]  = (bf16_t)((v1 - mean) * rs * g1 + b1);
        o[lane + 128] = (bf16_t)((v2 - mean) * rs * g2 + b2);
    }
    __syncthreads();

    // phase 3: obuf -> xw, 8 window-groups x 7 contiguous rows (int4 stores)
    const int hr = (h + 53) % 56;
    const int nh = hr / 7, ii = hr % 7;
    const long rband = ((long)b * 64 + (long)nh * 8) * 49 + (long)ii * 7;
    const int4* src = (const int4*)obuf;
    for (int q = tid; q < 1344; q += 1024) {
        const int g = q / 168, u = q % 168;
        const int jj = u / 24, ci = u % 24;
        const long r = rband + (long)g * 49 + jj;
        ((int4*)xw)[r * 24 + ci] = src[(g * 7 + jj) * 24 + ci];
    }
}

// ---- one-shot GEMM for K=192 (qkv): stage full panels, ONE barrier ------
template<int EPI, int N>
__global__ __launch_bounds__(256) void k_gemm_1s(const bf16_t* __restrict__ A,
                                                 const bf16_t* __restrict__ W,
                                                 const float* __restrict__ bias,
                                                 bf16_t* __restrict__ outp)
{
    __shared__ bf16_t As[64 * 192];   // 24 KB
    __shared__ bf16_t Bs[64 * 192];   // 24 KB
    const int tid = threadIdx.x;
    const int wv = tid >> 6, ln = tid & 63;
    const int lrow = ln & 15, lkg = ln >> 4;
    const int r7 = lrow & 7;
    const int wm = (wv >> 1) * 32, wn = (wv & 1) * 32;
    const long m0 = (long)blockIdx.x * 64;
    const int n0 = blockIdx.y * 64;

    #pragma unroll
    for (int i = 0; i < 6; ++i) {
        const int off = ((wv * 6 + i) << 10) + ln * 16;
        const int row = off / 384;
        const int slot = (off % 384) >> 4;
        const int col = ((slot & 24) | ((slot & 7) ^ (row & 7))) << 3;
        gl16(A + (m0 + row) * 192 + col, (char*)As + ((wv * 6 + i) << 10));
    }
    #pragma unroll
    for (int i = 0; i < 6; ++i) {
        const int off = ((wv * 6 + i) << 10) + ln * 16;
        const int row = off / 384;
        const int slot = (off % 384) >> 4;
        const int col = ((slot & 24) | ((slot & 7) ^ (row & 7))) << 3;
        gl16(W + (long)(n0 + row) * 192 + col, (char*)Bs + ((wv * 6 + i) << 10));
    }
    __syncthreads();

    f32x4 acc[2][2];
    #pragma unroll
    for (int mi = 0; mi < 2; ++mi)
        #pragma unroll
        for (int ni = 0; ni < 2; ++ni)
            #pragma unroll
            for (int rg = 0; rg < 4; ++rg) acc[mi][ni][rg] = 0.f;

    #pragma unroll
    for (int kk = 0; kk < 6; ++kk) {
        const int s = kk * 4 + lkg;
        const int kb = ((s & 24) | ((s & 7) ^ r7)) << 4;
        bf16x8 af[2], bfr[2];
        #pragma unroll
        for (int mi = 0; mi < 2; ++mi)
            af[mi] = *(const bf16x8*)((const char*)As
                       + (wm + mi * 16 + lrow) * 384 + kb);
        #pragma unroll
        for (int ni = 0; ni < 2; ++ni)
            bfr[ni] = *(const bf16x8*)((const char*)Bs
                       + (wn + ni * 16 + lrow) * 384 + kb);
        #pragma unroll
        for (int mi = 0; mi < 2; ++mi)
            #pragma unroll
            for (int ni = 0; ni < 2; ++ni)
                acc[mi][ni] = MFMA16(bfr[ni], af[mi], acc[mi][ni]);  // swapped
    }

    #pragma unroll
    for (int mi = 0; mi < 2; ++mi) {
        const long m = m0 + wm + mi * 16 + lrow;
        #pragma unroll
        for (int ni = 0; ni < 2; ++ni) {
            const int nb = n0 + wn + ni * 16 + lkg * 4;
            const float4 bv = *(const float4*)(bias + nb);
            float v[4] = { acc[mi][ni][0] + bv.x, acc[mi][ni][1] + bv.y,
                           acc[mi][ni][2] + bv.z, acc[mi][ni][3] + bv.w };
            bf16x4 o;
            #pragma unroll
            for (int rg = 0; rg < 4; ++rg) {
                float u = v[rg];
                if (EPI == 2) u = gelu_t(u);
                o[rg] = (bf16_t)u;
            }
            *(bf16x4*)(outp + m * N + nb) = o;
        }
    }
}

// ---- fused MLP: out = fc2(gelu(fc1(A))) for 64-token tiles --------------
// 4 quarters of 192 h-cols; per quarter 6 fc1-chunks (32 W1 rows) then
// 6 fc2-slices (32 k). fc2 acc lives in registers across quarters.
// W staged via register-prefetch (T14): loads issued during prev compute.
__global__ __launch_bounds__(256) void k_mlp(const bf16_t* __restrict__ A,
                                             const bf16_t* __restrict__ W1,
                                             const float* __restrict__ b1,
                                             const bf16_t* __restrict__ W2,
                                             const float* __restrict__ b2,
                                             bf16_t* __restrict__ outp)
{
    __shared__ bf16_t Xs[64 * 192];   // 24 KB  (X tile, swizzled)
    __shared__ bf16_t Hq[64 * 192];   // 24 KB  (h quarter, swizzled)
    __shared__ bf16_t Ws[32 * 192];   // 12 KB  (W1 chunk [32][192] / W2 slice [192][32])
    const int tid = threadIdx.x;
    const int wv = tid >> 6, ln = tid & 63;
    const int lrow = ln & 15, lkg = ln >> 4;
    const long m0 = (long)blockIdx.x * 64;
    const int wm = (wv >> 1) * 32;     // m split
    const int wn16 = (wv & 1) * 16;    // fc1 n split (within 32-chunk)
    const int wn96 = (wv & 1) * 96;    // fc2 n split (within 192)

    // stage X tile (pre-swizzled source, linear LDS dest)
    #pragma unroll
    for (int i = 0; i < 6; ++i) {
        const int off = ((wv * 6 + i) << 10) + ln * 16;
        const int row = off / 384;
        const int slot = (off % 384) >> 4;
        const int col = ((slot & 24) | ((slot & 7) ^ (row & 7))) << 3;
        gl16(A + (m0 + row) * 192 + col, (char*)Xs + ((wv * 6 + i) << 10));
    }

    // per-thread W staging geometry (both layouts), precomputed
    int ldsoff[3]; long w1off[3], w2off[3];
    #pragma unroll
    for (int i = 0; i < 3; ++i) {
        const int off = ((wv * 3 + i) << 10) + ln * 16;
        ldsoff[i] = off;
        const int ra1 = off / 384, sa1 = (off % 384) >> 4;           // [32][384B]
        w1off[i] = (long)ra1 * 192 + (((sa1 & 24) | ((sa1 & 7) ^ (ra1 & 7))) << 3);
        const int ra2 = off >> 6, sa2 = (off >> 4) & 3;              // [192][64B]
        w2off[i] = (long)ra2 * 768 + ((sa2 ^ (ra2 & 3)) << 3);
    }

    int4 ra, rb, rc;
    auto issue = [&](int qn, int rn) {
        if (rn < 6) {
            const bf16_t* b = W1 + (long)(qn * 192 + rn * 32) * 192;
            ra = *(const int4*)(b + w1off[0]);
            rb = *(const int4*)(b + w1off[1]);
            rc = *(const int4*)(b + w1off[2]);
        } else {
            const bf16_t* b = W2 + qn * 192 + (rn - 6) * 32;
            ra = *(const int4*)(b + w2off[0]);
            rb = *(const int4*)(b + w2off[1]);
            rc = *(const int4*)(b + w2off[2]);
        }
    };

    f32x4 acc2[2][6];
    #pragma unroll
    for (int mi = 0; mi < 2; ++mi)
        #pragma unroll
        for (int ni = 0; ni < 6; ++ni)
            #pragma unroll
            for (int rg = 0; rg < 4; ++rg) acc2[mi][ni][rg] = 0.f;

    issue(0, 0);
    __syncthreads();           // Xs staged

    int q = 0, r = 0;
    #pragma unroll 1
    for (int p = 0; p < 48; ++p) {
        // write prefetched W phase into LDS (vmcnt wait auto via reg dep)
        *(int4*)((char*)Ws + ldsoff[0]) = ra;
        *(int4*)((char*)Ws + ldsoff[1]) = rb;
        *(int4*)((char*)Ws + ldsoff[2]) = rc;
        __syncthreads();
        // prefetch next phase's W
        int qn = q, rn = r + 1;
        if (rn == 12) { rn = 0; qn = q + 1; }
        if (p + 1 < 48) issue(qn, rn);

        if (r < 6) {
            // ---- fc1 chunk c=r of quarter q: h[64][32] = X @ W1c^T ----
            f32x4 acc1[2];
            #pragma unroll
            for (int mi = 0; mi < 2; ++mi)
                #pragma unroll
                for (int rg = 0; rg < 4; ++rg) acc1[mi][rg] = 0.f;
            #pragma unroll
            for (int kk = 0; kk < 6; ++kk) {
                const int sb = kk * 4 + lkg;
                const int rowb = wn16 + lrow;
                bf16x8 bfr = *(const bf16x8*)((const char*)Ws + rowb * 384
                               + (((sb & 24) | ((sb & 7) ^ (rowb & 7))) << 4));
                #pragma unroll
                for (int mi = 0; mi < 2; ++mi) {
                    const int rowa = wm + mi * 16 + lrow;
                    bf16x8 af = *(const bf16x8*)((const char*)Xs + rowa * 384
                                  + (((sb & 24) | ((sb & 7) ^ (rowa & 7))) << 4));
                    acc1[mi] = MFMA16(bfr, af, acc1[mi]);
                }
            }
            const int qcol = r * 32 + wn16 + lkg * 4;
            const float4 bv = *(const float4*)(b1 + q * 192 + qcol);
            const int slot = qcol >> 3;
            #pragma unroll
            for (int mi = 0; mi < 2; ++mi) {
                const int rowm = wm + mi * 16 + lrow;
                bf16x4 o;
                o[0] = (bf16_t)gelu_t(acc1[mi][0] + bv.x);
                o[1] = (bf16_t)gelu_t(acc1[mi][1] + bv.y);
                o[2] = (bf16_t)gelu_t(acc1[mi][2] + bv.z);
                o[3] = (bf16_t)gelu_t(acc1[mi][3] + bv.w);
                *(bf16x4*)((char*)Hq + rowm * 384
                    + (((slot & 24) | ((slot & 7) ^ (rowm & 7))) << 4)
                    + ((qcol & 7) << 1)) = o;
            }
        } else {
            // ---- fc2 slice ks=r-6: acc2 += Hq[:, ks*32..] @ W2s^T ----
            const int sh = (r - 6) * 4 + lkg;
            bf16x8 af[2];
            #pragma unroll
            for (int mi = 0; mi < 2; ++mi) {
                const int rowa = wm + mi * 16 + lrow;
                af[mi] = *(const bf16x8*)((const char*)Hq + rowa * 384
                           + (((sh & 24) | ((sh & 7) ^ (rowa & 7))) << 4));
            }
            #pragma unroll
            for (int ni = 0; ni < 6; ++ni) {
                const int rowb = wn96 + ni * 16 + lrow;
                bf16x8 bfr = *(const bf16x8*)((const char*)Ws + rowb * 64
                               + ((lkg ^ (rowb & 3)) << 4));
                #pragma unroll
                for (int mi = 0; mi < 2; ++mi)
                    acc2[mi][ni] = MFMA16(bfr, af[mi], acc2[mi][ni]);
            }
        }
        __syncthreads();
        q = qn; r = rn;
    }

    // final epilogue: out[64][192]
    #pragma unroll
    for (int mi = 0; mi < 2; ++mi) {
        const long m = m0 + wm + mi * 16 + lrow;
        #pragma unroll
        for (int ni = 0; ni < 6; ++ni) {
            const int nb = wn96 + ni * 16 + lkg * 4;
            const float4 bv = *(const float4*)(b2 + nb);
            bf16x4 o;
            o[0] = (bf16_t)(acc2[mi][ni][0] + bv.x);
            o[1] = (bf16_t)(acc2[mi][ni][1] + bv.y);
            o[2] = (bf16_t)(acc2[mi][ni][2] + bv.z);
            o[3] = (bf16_t)(acc2[mi][ni][3] + bv.w);
            *(bf16x4*)(outp + m * 192 + nb) = o;
        }
    }
}

// ------- proj GEMM (N=192, K=192) + fused LN2, 64-row blocks -------------
__global__ __launch_bounds__(256) void k_proj_ln(const bf16_t* __restrict__ A,
                                                 const bf16_t* __restrict__ W,
                                                 const float* __restrict__ bias,
                                                 const float* __restrict__ gam,
                                                 const float* __restrict__ bet,
                                                 bf16_t* __restrict__ out)
{
    __shared__ bf16_t As[64][72];    // 9 KB
    __shared__ bf16_t Bs[192][72];   // 27 KB
    const int tid = threadIdx.x;
    const int wave = tid >> 6, lane = tid & 63;
    const int lrow = lane & 15, lkg = lane >> 4;
    const int wm = wave * 16;
    const long m0 = (long)blockIdx.x * 64;

    f32x4 acc[12];
    #pragma unroll
    for (int ni = 0; ni < 12; ++ni)
        #pragma unroll
        for (int rg = 0; rg < 4; ++rg) acc[ni][rg] = 0.f;

    for (int k0 = 0; k0 < 192; k0 += 64) {
        #pragma unroll
        for (int it = 0; it < 2; ++it) {
            int e = (tid + it * 256) * 8;
            int r = e >> 6, c = e & 63;
            *(int4*)(&As[r][c]) = *(const int4*)(A + (m0 + r) * 192 + (k0 + c));
        }
        #pragma unroll
        for (int it = 0; it < 6; ++it) {
            int e = (tid + it * 256) * 8;
            int r = e >> 6, c = e & 63;
            *(int4*)(&Bs[r][c]) = *(const int4*)(W + (long)r * 192 + (k0 + c));
        }
        __syncthreads();
        #pragma unroll
        for (int kk = 0; kk < 64; kk += 32) {
            bf16x8 af = *(const bf16x8*)(&As[wm + lrow][kk + lkg * 8]);
            #pragma unroll
            for (int ni = 0; ni < 12; ++ni) {
                bf16x8 bfr = *(const bf16x8*)(&Bs[ni * 16 + lrow][kk + lkg * 8]);
                acc[ni] = MFMA16(af, bfr, acc[ni]);
            }
        }
        __syncthreads();
    }

    float bv[12];
    #pragma unroll
    for (int ni = 0; ni < 12; ++ni) bv[ni] = bias[ni * 16 + lrow];

    #pragma unroll
    for (int rg = 0; rg < 4; ++rg) {
        float val[12];
        float s = 0.f, sq = 0.f;
        #pragma unroll
        for (int ni = 0; ni < 12; ++ni) {
            val[ni] = acc[ni][rg] + bv[ni];
            s += val[ni];
            sq += val[ni] * val[ni];
        }
        #pragma unroll
        for (int d = 1; d < 16; d <<= 1) {
            s += __shfl_xor(s, d);
            sq += __shfl_xor(sq, d);
        }
        float mean = s * (1.f / 192.f);
        float var  = sq * (1.f / 192.f) - mean * mean;
        float rs = rsqrtf(var + 1e-5f);
        const long row = m0 + wm + lkg * 4 + rg;
        bf16_t* orow = out + row * 192;
        #pragma unroll
        for (int ni = 0; ni < 12; ++ni) {
            const int col = ni * 16 + lrow;
            orow[col] = (bf16_t)((val[ni] - mean) * rs * gam[col] + bet[col]);
        }
    }
}

// ---------------- window attention: 1 wave per (window, head) ------------
__global__ __launch_bounds__(64) void k_attn(const bf16_t* __restrict__ qkv,
                                             bf16_t* __restrict__ aout)
{
    __shared__ bf16_t Pl[64][72];
    __shared__ bf16_t Vt[32][72];   // V transposed: Vt[d][m]
    const int win = blockIdx.x, head = blockIdx.y;
    const int lane = threadIdx.x;
    const int lrow = lane & 15, lkg = lane >> 4;
    const bf16_t* base = qkv + (long)win * 28224 + head * 32;  // 49*576

    // stage V^T into LDS (rows m>=49 zeroed)
    {
        const int m = lane;
        const int mc = (m < 49) ? m : 48;
        const int4* vr = (const int4*)(base + (long)mc * 576 + 384);
        #pragma unroll
        for (int c4 = 0; c4 < 4; ++c4) {
            int4 vv = vr[c4];
            if (m >= 49) vv = make_int4(0, 0, 0, 0);
            const bf16_t* pe = (const bf16_t*)&vv;
            #pragma unroll
            for (int e = 0; e < 8; ++e) Vt[c4 * 8 + e][m] = pe[e];
        }
    }

    // QK^T: S[n][m] = sum_d q[n][d] k[m][d], padded 49->64
    bf16x8 z8;
    #pragma unroll
    for (int e = 0; e < 8; ++e) z8[e] = (bf16_t)0.f;
    bf16x8 qf[4], kf[4];
    #pragma unroll
    for (int t = 0; t < 4; ++t) {
        const int n = t * 16 + lrow;
        const int nc = (n < 49) ? n : 48;
        bf16x8 qv = *(const bf16x8*)(base + (long)nc * 576 + lkg * 8);
        bf16x8 kv = *(const bf16x8*)(base + (long)nc * 576 + 192 + lkg * 8);
        qf[t] = (n < 49) ? qv : z8;
        kf[t] = (n < 49) ? kv : z8;
    }
    f32x4 zf; zf[0] = zf[1] = zf[2] = zf[3] = 0.f;
    f32x4 S[4][4];
    #pragma unroll
    for (int mi = 0; mi < 4; ++mi)
        #pragma unroll
        for (int mj = 0; mj < 4; ++mj)
            S[mi][mj] = MFMA16(qf[mi], kf[mj], zf);

    // row softmax (cols >= 49 masked), P -> LDS as bf16
    const float scl = 0.17677669529663687f;   // 32^-0.5
    #pragma unroll
    for (int mi = 0; mi < 4; ++mi) {
        #pragma unroll
        for (int rg = 0; rg < 4; ++rg) {
            float v0 = S[mi][0][rg] * scl;
            float v1 = S[mi][1][rg] * scl;
            float v2 = S[mi][2][rg] * scl;
            float v3 = (lrow == 0) ? S[mi][3][rg] * scl : -1e30f;  // col 48+lrow
            float mx = fmaxf(fmaxf(v0, v1), fmaxf(v2, v3));
            #pragma unroll
            for (int d = 1; d < 16; d <<= 1) mx = fmaxf(mx, __shfl_xor(mx, d));
            float e0 = expf(v0 - mx), e1 = expf(v1 - mx), e2 = expf(v2 - mx);
            float e3 = (lrow == 0) ? expf(v3 - mx) : 0.f;
            float sm = e0 + e1 + e2 + e3;
            #pragma unroll
            for (int d = 1; d < 16; d <<= 1) sm += __shfl_xor(sm, d);
            float is = 1.f / sm;
            const int row = mi * 16 + lkg * 4 + rg;
            Pl[row][lrow]      = (bf16_t)(e0 * is);
            Pl[row][16 + lrow] = (bf16_t)(e1 * is);
            Pl[row][32 + lrow] = (bf16_t)(e2 * is);
            Pl[row][48 + lrow] = (bf16_t)(e3 * is);
        }
    }
    __syncthreads();

    // PV: out[n][d] = sum_m P[n][m] Vt[d][m]
    f32x4 o[4][2];
    #pragma unroll
    for (int ni = 0; ni < 4; ++ni)
        #pragma unroll
        for (int di = 0; di < 2; ++di)
            #pragma unroll
            for (int rg = 0; rg < 4; ++rg) o[ni][di][rg] = 0.f;
    #pragma unroll
    for (int m0 = 0; m0 < 64; m0 += 32) {
        bf16x8 pf[4], vf[2];
        #pragma unroll
        for (int ni = 0; ni < 4; ++ni)
            pf[ni] = *(const bf16x8*)(&Pl[ni * 16 + lrow][m0 + lkg * 8]);
        #pragma unroll
        for (int di = 0; di < 2; ++di)
            vf[di] = *(const bf16x8*)(&Vt[di * 16 + lrow][m0 + lkg * 8]);
        #pragma unroll
        for (int ni = 0; ni < 4; ++ni)
            #pragma unroll
            for (int di = 0; di < 2; ++di)
                o[ni][di] = MFMA16(pf[ni], vf[di], o[ni][di]);
    }
    #pragma unroll
    for (int ni = 0; ni < 4; ++ni) {
        #pragma unroll
        for (int rg = 0; rg < 4; ++rg) {
            const int n = ni * 16 + lkg * 4 + rg;
            if (n < 49) {
                bf16_t* orow = aout + ((long)win * 49 + n) * 192 + head * 32;
                orow[lrow]      = (bf16_t)o[ni][0][rg];
                orow[16 + lrow] = (bf16_t)o[ni][1][rg];
            }
        }
    }
}

// ---------------- final: un-window + roll(+3) + BHWC->BCHW + shortcut ----
__global__ __launch_bounds__(1024) void k_final(const bf16_t* __restrict__ fb,
                                                const float* __restrict__ x,
                                                float* __restrict__ out)
{
    __shared__ float tile[56][199];   // odd-ish stride: conflict-free col reads
    const int bh = blockIdx.x;
    const int b = bh / 56, hq = bh % 56;
    const int tid = threadIdx.x;
    const int hr = (hq + 53) % 56;
    const int nh = hr / 7, ii = hr % 7;
    const long rband = ((long)b * 64 + (long)nh * 8) * 49 + (long)ii * 7;

    // phase 1: gather fb rows (contiguous 384B/row) into tile[wq][c]
    for (int q = tid; q < 1344; q += 1024) {
        const int g = q / 168, rem = q % 168;
        const int jj = rem / 24, ci = rem % 24;
        const long rr = rband + (long)g * 49 + jj;
        bf16x8 v = *(const bf16x8*)(fb + rr * 192 + ci * 8);
        const int wq = (g * 7 + jj + 3) % 56;
        #pragma unroll
        for (int e = 0; e < 8; ++e) tile[wq][ci * 8 + e] = (float)v[e];
    }
    __syncthreads();

    // phase 2: out[b][c][hq][w] = tile[w][c] + x[b][c][hq][w]  (float4 along w)
    const int g = tid >> 4, u = tid & 15;
    if (u < 14) {
        #pragma unroll
        for (int k = 0; k < 3; ++k) {
            const int c = g + 64 * k;
            const long base = ((long)b * 192 + c) * 3136 + (long)hq * 56 + u * 4;
            float4 xv = *(const float4*)(x + base);
            float4 ov;
            ov.x = tile[u * 4 + 0][c] + xv.x;
            ov.y = tile[u * 4 + 1][c] + xv.y;
            ov.z = tile[u * 4 + 2][c] + xv.z;
            ov.w = tile[u * 4 + 3][c] + xv.w;
            *(float4*)(out + base) = ov;
        }
    }
}

extern "C" void kernel_launch(void* const* d_in, const int* in_sizes, int n_in,
                              void* d_out, int out_size, void* d_ws, size_t ws_size,
                              hipStream_t stream)
{
    const float* x     = (const float*)d_in[0];
    const float* n1w   = (const float*)d_in[1];
    const float* n1b   = (const float*)d_in[2];
    const float* qkvw  = (const float*)d_in[3];
    const float* qkvb  = (const float*)d_in[4];
    const float* projw = (const float*)d_in[5];
    const float* projb = (const float*)d_in[6];
    const float* n2w   = (const float*)d_in[7];
    const float* n2b   = (const float*)d_in[8];
    const float* fc1w  = (const float*)d_in[9];
    const float* fc1b  = (const float*)d_in[10];
    const float* fc2w  = (const float*)d_in[11];
    const float* fc2b  = (const float*)d_in[12];

    char* ws = (char*)d_ws;
    bf16_t* wqkv  = (bf16_t*)(ws);              // 576*192  bf16
    bf16_t* wproj = (bf16_t*)(ws + 221184);     // 192*192
    bf16_t* wfc1  = (bf16_t*)(ws + 294912);     // 768*192
    bf16_t* wfc2  = (bf16_t*)(ws + 589824);     // 192*768
    bf16_t* Xb    = (bf16_t*)(ws + 884736);     // [50176][192] bf16 (LN1 out, attn out)
    bf16_t* QKV   = (bf16_t*)(ws + 20152320);   // [50176][576] bf16
    bf16_t* H2    = (bf16_t*)(ws + 155025408);  // [50176][192] bf16 (mlp out)
    bf16_t* X2    = (bf16_t*)(ws + 174292992);  // [50176][192] bf16 (LN2 out)

    k_cvt<<<1728, 256, 0, stream>>>(qkvw, projw, fc1w, fc2w, wqkv);
    k_ln1<<<896, 1024, 0, stream>>>(x, n1w, n1b, Xb);
    k_gemm_1s<0, 576><<<dim3(784, 9), 256, 0, stream>>>(Xb, wqkv, qkvb, QKV);
    k_attn<<<dim3(1024, 6), 64, 0, stream>>>(QKV, Xb);
    k_proj_ln<<<784, 256, 0, stream>>>(Xb, wproj, projb, n2w, n2b, X2);
    k_mlp<<<784, 256, 0, stream>>>(X2, wfc1, fc1b, wfc2, fc2b, H2);
    k_final<<<896, 1024, 0, stream>>>(H2, x, (float*)d_out);
}

// Round 11
// 216.888 us; speedup vs baseline: 1.0525x; 1.0525x over previous
//
#include <hip/hip_runtime.h>
#include <hip/hip_bf16.h>

typedef __bf16 bf16_t;
typedef __bf16 bf16x4 __attribute__((ext_vector_type(4)));
typedef __bf16 bf16x8 __attribute__((ext_vector_type(8)));
typedef float f32x4 __attribute__((ext_vector_type(4)));

#define MFMA16(a, b, c) __builtin_amdgcn_mfma_f32_16x16x32_bf16((a), (b), (c), 0, 0, 0)

// async global->LDS, 16B per lane; dest = wave-uniform base + lane*16
__device__ __forceinline__ void gl16(const bf16_t* g, void* l) {
    __builtin_amdgcn_global_load_lds(
        (const __attribute__((address_space(1))) void*)g,
        (__attribute__((address_space(3))) void*)l, 16, 0, 0);
}

__device__ __forceinline__ float gelu_t(float u) {
    float t2 = fminf(u * (1.5957691216057308f + 0.07135481627f * u * u), 60.f);
    float e = __expf(t2);
    return u * e / (e + 1.f);
}

// Problem constants
// B=16, C=192, H=W=56, WIN=7, SHIFT=3, HEADS=6, DH=32, HID=768
// tokens M = 16*8*8*49 = 50176, windows = 1024

// ---------------- weight convert (4 weights -> contiguous bf16) ----------
__global__ __launch_bounds__(256) void k_cvt(const float* __restrict__ qkvw,
                                             const float* __restrict__ projw,
                                             const float* __restrict__ fc1w,
                                             const float* __restrict__ fc2w,
                                             bf16_t* __restrict__ dst)
{
    int i = blockIdx.x * 256 + threadIdx.x;
    if (i >= 442368) return;
    float v;
    if (i < 110592)      v = qkvw[i];
    else if (i < 147456) v = projw[i - 110592];
    else if (i < 294912) v = fc1w[i - 147456];
    else                 v = fc2w[i - 294912];
    dst[i] = (bf16_t)v;
}

// ---------------- LN1 + roll(-3) + window partition -> xw bf16 -----------
__global__ __launch_bounds__(1024) void k_ln1(const float* __restrict__ x,
                                              const float* __restrict__ gam,
                                              const float* __restrict__ bet,
                                              bf16_t* __restrict__ xw)
{
    __shared__ float tile[56][193];     // odd stride: conflict-free row reads
    __shared__ bf16_t obuf[56 * 192];   // row stride 384B = 24 int4
    const int bh = blockIdx.x;
    const int b = bh / 56, h = bh % 56;
    const int tid = threadIdx.x;

    // phase 1: x[b][:][h][:] -> tile[w][c] (float4 global loads)
    {
        const int g = tid >> 4, u = tid & 15;   // g: channel group 0..63
        const float* xb = x + (long)b * 602112 + (long)h * 56;
        if (u < 14) {
            #pragma unroll
            for (int k = 0; k < 3; ++k) {
                const int c = g + 64 * k;
                float4 v = *(const float4*)(xb + (long)c * 3136 + u * 4);
                tile[u * 4 + 0][c] = v.x;
                tile[u * 4 + 1][c] = v.y;
                tile[u * 4 + 2][c] = v.z;
                tile[u * 4 + 3][c] = v.w;
            }
        }
    }
    __syncthreads();

    // phase 2: LN per token (wave-parallel over w), bf16 -> obuf by rolled idx
    const int wave = tid >> 6, lane = tid & 63;
    const float g0 = gam[lane], g1 = gam[lane + 64], g2 = gam[lane + 128];
    const float b0 = bet[lane], b1 = bet[lane + 64], b2 = bet[lane + 128];
    for (int wp = wave; wp < 56; wp += 16) {
        float v0 = tile[wp][lane], v1 = tile[wp][lane + 64], v2 = tile[wp][lane + 128];
        float s = v0 + v1 + v2;
        float sq = v0 * v0 + v1 * v1 + v2 * v2;
        #pragma unroll
        for (int d = 1; d < 64; d <<= 1) { s += __shfl_xor(s, d); sq += __shfl_xor(sq, d); }
        float mean = s * (1.f / 192.f);
        float var  = sq * (1.f / 192.f) - mean * mean;
        float rs = rsqrtf(var + 1e-5f);
        const int wr = (wp + 53) % 56;
        bf16_t* o = obuf + wr * 192;
        o[lane]       = (bf16_t)((v0 - mean) * rs * g0 + b0);
        o[lane + 64]  = (bf16_t)((v1 - mean) * rs * g1 + b1);
        o[lane + 128] = (bf16_t)((v2 - mean) * rs * g2 + b2);
    }
    __syncthreads();

    // phase 3: obuf -> xw, 8 window-groups x 7 contiguous rows (int4 stores)
    const int hr = (h + 53) % 56;
    const int nh = hr / 7, ii = hr % 7;
    const long rband = ((long)b * 64 + (long)nh * 8) * 49 + (long)ii * 7;
    const int4* src = (const int4*)obuf;
    for (int q = tid; q < 1344; q += 1024) {
        const int g = q / 168, u = q % 168;
        const int jj = u / 24, ci = u % 24;
        const long r = rband + (long)g * 49 + jj;
        ((int4*)xw)[r * 24 + ci] = src[(g * 7 + jj) * 24 + ci];
    }
}

// ---- one-shot GEMM K=192, block 64m x 96n, wave 32x48 (36 MFMA/wave) ----
// Full A/B panels staged once (gl16, swizzle pair), ONE barrier per block.
// grid = (N/96, M/64): n-slices fast -> co-resident blocks share A in L2.
// EPI: 0 = bf16 out, 2 = bf16 out + tanh-GELU
template<int EPI, int N>
__global__ __launch_bounds__(256) void k_gemm96(const bf16_t* __restrict__ A,
                                                const bf16_t* __restrict__ W,
                                                const float* __restrict__ bias,
                                                bf16_t* __restrict__ outp)
{
    __shared__ bf16_t As[64 * 192];   // 24 KB
    __shared__ bf16_t Bs[96 * 192];   // 36 KB
    const int tid = threadIdx.x;
    const int wv = tid >> 6, ln = tid & 63;
    const int lrow = ln & 15, lkg = ln >> 4;
    const int r7 = lrow & 7;
    const int wm = (wv >> 1) * 32, wn = (wv & 1) * 48;   // 48%8==0: swizzle ok
    const long m0 = (long)blockIdx.y * 64;
    const int n0 = blockIdx.x * 96;

    // stage A[64][192]: 24 x 1KB chunks (6/wave), source pre-swizzled
    #pragma unroll
    for (int i = 0; i < 6; ++i) {
        const int off = ((wv * 6 + i) << 10) + ln * 16;
        const int row = off / 384;
        const int slot = (off % 384) >> 4;
        const int col = ((slot & 24) | ((slot & 7) ^ (row & 7))) << 3;
        gl16(A + (m0 + row) * 192 + col, (char*)As + ((wv * 6 + i) << 10));
    }
    // stage B[96][192]: 36 x 1KB chunks (9/wave)
    #pragma unroll
    for (int i = 0; i < 9; ++i) {
        const int off = ((wv * 9 + i) << 10) + ln * 16;
        const int row = off / 384;
        const int slot = (off % 384) >> 4;
        const int col = ((slot & 24) | ((slot & 7) ^ (row & 7))) << 3;
        gl16(W + (long)(n0 + row) * 192 + col, (char*)Bs + ((wv * 9 + i) << 10));
    }
    __syncthreads();   // the ONLY barrier

    f32x4 acc[2][3];
    #pragma unroll
    for (int mi = 0; mi < 2; ++mi)
        #pragma unroll
        for (int ni = 0; ni < 3; ++ni)
            #pragma unroll
            for (int rg = 0; rg < 4; ++rg) acc[mi][ni][rg] = 0.f;

    #pragma unroll
    for (int kk = 0; kk < 6; ++kk) {
        const int s = kk * 4 + lkg;                       // logical slot 0..23
        const int kb = ((s & 24) | ((s & 7) ^ r7)) << 4;  // swizzled byte
        bf16x8 af[2], bfr[3];
        #pragma unroll
        for (int mi = 0; mi < 2; ++mi)
            af[mi] = *(const bf16x8*)((const char*)As
                       + (wm + mi * 16 + lrow) * 384 + kb);
        #pragma unroll
        for (int ni = 0; ni < 3; ++ni)
            bfr[ni] = *(const bf16x8*)((const char*)Bs
                       + (wn + ni * 16 + lrow) * 384 + kb);
        #pragma unroll
        for (int mi = 0; mi < 2; ++mi)
            #pragma unroll
            for (int ni = 0; ni < 3; ++ni)
                acc[mi][ni] = MFMA16(bfr[ni], af[mi], acc[mi][ni]);  // swapped
    }

    // epilogue: m = ..+lrow, n = ..+lkg*4+rg -> 8B stores
    #pragma unroll
    for (int mi = 0; mi < 2; ++mi) {
        const long m = m0 + wm + mi * 16 + lrow;
        #pragma unroll
        for (int ni = 0; ni < 3; ++ni) {
            const int nb = n0 + wn + ni * 16 + lkg * 4;
            const float4 bv = *(const float4*)(bias + nb);
            float v[4] = { acc[mi][ni][0] + bv.x, acc[mi][ni][1] + bv.y,
                           acc[mi][ni][2] + bv.z, acc[mi][ni][3] + bv.w };
            bf16x4 o;
            #pragma unroll
            for (int rg = 0; rg < 4; ++rg) {
                float u = v[rg];
                if (EPI == 2) u = gelu_t(u);
                o[rg] = (bf16_t)u;
            }
            *(bf16x4*)(outp + m * N + nb) = o;
        }
    }
}

// ---------------- GEMM 128x64 (single-buffer) — used for fc2 (K=768) -----
template<int EPI, int N, int K>
__global__ __launch_bounds__(256) void k_gemm(const bf16_t* __restrict__ A,
                                              const bf16_t* __restrict__ W,
                                              const float* __restrict__ bias,
                                              bf16_t* __restrict__ outp)
{
    __shared__ bf16_t As[128 * 64];
    __shared__ bf16_t Bs[64 * 64];
    const int tid = threadIdx.x;
    const int wv = tid >> 6, ln = tid & 63;
    const int lrow = ln & 15, lkg = ln >> 4;
    const int r7 = lrow & 7;
    const int wm = (wv >> 1) * 64, wn = (wv & 1) * 32;
    const long m0 = (long)blockIdx.x * 128;
    const int n0 = blockIdx.y * 64;

    f32x4 acc[4][2];
    #pragma unroll
    for (int mi = 0; mi < 4; ++mi)
        #pragma unroll
        for (int ni = 0; ni < 2; ++ni)
            #pragma unroll
            for (int rg = 0; rg < 4; ++rg) acc[mi][ni][rg] = 0.f;

    for (int t = 0; t < K / 64; ++t) {
        #pragma unroll
        for (int i = 0; i < 4; ++i) {
            const int off = ((wv * 4 + i) << 10) + ln * 16;
            const int row = off >> 7;
            const int c16 = ((off >> 4) & 7) ^ (row & 7);
            gl16(A + (m0 + row) * K + t * 64 + (c16 << 3),
                 (char*)As + ((wv * 4 + i) << 10));
        }
        #pragma unroll
        for (int i = 0; i < 2; ++i) {
            const int off = ((wv * 2 + i) << 10) + ln * 16;
            const int row = off >> 7;
            const int c16 = ((off >> 4) & 7) ^ (row & 7);
            gl16(W + (long)(n0 + row) * K + t * 64 + (c16 << 3),
                 (char*)Bs + ((wv * 2 + i) << 10));
        }
        __syncthreads();
        #pragma unroll
        for (int kk = 0; kk < 2; ++kk) {
            const int kb = (((kk << 2) | lkg) ^ r7) << 4;
            bf16x8 af[4], bfr[2];
            #pragma unroll
            for (int mi = 0; mi < 4; ++mi)
                af[mi] = *(const bf16x8*)((const char*)As
                           + (wm + mi * 16 + lrow) * 128 + kb);
            #pragma unroll
            for (int ni = 0; ni < 2; ++ni)
                bfr[ni] = *(const bf16x8*)((const char*)Bs
                           + (wn + ni * 16 + lrow) * 128 + kb);
            #pragma unroll
            for (int mi = 0; mi < 4; ++mi)
                #pragma unroll
                for (int ni = 0; ni < 2; ++ni)
                    acc[mi][ni] = MFMA16(bfr[ni], af[mi], acc[mi][ni]); // swapped
        }
        __syncthreads();
    }

    #pragma unroll
    for (int mi = 0; mi < 4; ++mi) {
        const long m = m0 + wm + mi * 16 + lrow;
        #pragma unroll
        for (int ni = 0; ni < 2; ++ni) {
            const int nb = n0 + wn + ni * 16 + lkg * 4;
            const float4 bv = *(const float4*)(bias + nb);
            float v[4] = { acc[mi][ni][0] + bv.x, acc[mi][ni][1] + bv.y,
                           acc[mi][ni][2] + bv.z, acc[mi][ni][3] + bv.w };
            bf16x4 o;
            #pragma unroll
            for (int rg = 0; rg < 4; ++rg) {
                float u = v[rg];
                if (EPI == 2) u = gelu_t(u);
                o[rg] = (bf16_t)u;
            }
            *(bf16x4*)(outp + m * N + nb) = o;
        }
    }
}

// ------- proj GEMM (N=192, K=192) + fused LN2, 64-row blocks -------------
__global__ __launch_bounds__(256) void k_proj_ln(const bf16_t* __restrict__ A,
                                                 const bf16_t* __restrict__ W,
                                                 const float* __restrict__ bias,
                                                 const float* __restrict__ gam,
                                                 const float* __restrict__ bet,
                                                 bf16_t* __restrict__ out)
{
    __shared__ bf16_t As[64][72];    // 9 KB
    __shared__ bf16_t Bs[192][72];   // 27 KB
    const int tid = threadIdx.x;
    const int wave = tid >> 6, lane = tid & 63;
    const int lrow = lane & 15, lkg = lane >> 4;
    const int wm = wave * 16;
    const long m0 = (long)blockIdx.x * 64;

    f32x4 acc[12];
    #pragma unroll
    for (int ni = 0; ni < 12; ++ni)
        #pragma unroll
        for (int rg = 0; rg < 4; ++rg) acc[ni][rg] = 0.f;

    for (int k0 = 0; k0 < 192; k0 += 64) {
        #pragma unroll
        for (int it = 0; it < 2; ++it) {
            int e = (tid + it * 256) * 8;
            int r = e >> 6, c = e & 63;
            *(int4*)(&As[r][c]) = *(const int4*)(A + (m0 + r) * 192 + (k0 + c));
        }
        #pragma unroll
        for (int it = 0; it < 6; ++it) {
            int e = (tid + it * 256) * 8;
            int r = e >> 6, c = e & 63;
            *(int4*)(&Bs[r][c]) = *(const int4*)(W + (long)r * 192 + (k0 + c));
        }
        __syncthreads();
        #pragma unroll
        for (int kk = 0; kk < 64; kk += 32) {
            bf16x8 af = *(const bf16x8*)(&As[wm + lrow][kk + lkg * 8]);
            #pragma unroll
            for (int ni = 0; ni < 12; ++ni) {
                bf16x8 bfr = *(const bf16x8*)(&Bs[ni * 16 + lrow][kk + lkg * 8]);
                acc[ni] = MFMA16(af, bfr, acc[ni]);
            }
        }
        __syncthreads();
    }

    float bv[12];
    #pragma unroll
    for (int ni = 0; ni < 12; ++ni) bv[ni] = bias[ni * 16 + lrow];

    #pragma unroll
    for (int rg = 0; rg < 4; ++rg) {
        float val[12];
        float s = 0.f, sq = 0.f;
        #pragma unroll
        for (int ni = 0; ni < 12; ++ni) {
            val[ni] = acc[ni][rg] + bv[ni];
            s += val[ni];
            sq += val[ni] * val[ni];
        }
        #pragma unroll
        for (int d = 1; d < 16; d <<= 1) {
            s += __shfl_xor(s, d);
            sq += __shfl_xor(sq, d);
        }
        float mean = s * (1.f / 192.f);
        float var  = sq * (1.f / 192.f) - mean * mean;
        float rs = rsqrtf(var + 1e-5f);
        const long row = m0 + wm + lkg * 4 + rg;
        bf16_t* orow = out + row * 192;
        #pragma unroll
        for (int ni = 0; ni < 12; ++ni) {
            const int col = ni * 16 + lrow;
            orow[col] = (bf16_t)((val[ni] - mean) * rs * gam[col] + bet[col]);
        }
    }
}

// ---------------- window attention: 1 wave per (window, head) ------------
__global__ __launch_bounds__(64) void k_attn(const bf16_t* __restrict__ qkv,
                                             bf16_t* __restrict__ aout)
{
    __shared__ bf16_t Pl[64][72];
    __shared__ bf16_t Vt[32][72];   // V transposed: Vt[d][m]
    const int win = blockIdx.x, head = blockIdx.y;
    const int lane = threadIdx.x;
    const int lrow = lane & 15, lkg = lane >> 4;
    const bf16_t* base = qkv + (long)win * 28224 + head * 32;  // 49*576

    // stage V^T into LDS (rows m>=49 zeroed)
    {
        const int m = lane;
        const int mc = (m < 49) ? m : 48;
        const int4* vr = (const int4*)(base + (long)mc * 576 + 384);
        #pragma unroll
        for (int c4 = 0; c4 < 4; ++c4) {
            int4 vv = vr[c4];
            if (m >= 49) vv = make_int4(0, 0, 0, 0);
            const bf16_t* pe = (const bf16_t*)&vv;
            #pragma unroll
            for (int e = 0; e < 8; ++e) Vt[c4 * 8 + e][m] = pe[e];
        }
    }

    // QK^T: S[n][m] = sum_d q[n][d] k[m][d], padded 49->64
    bf16x8 z8;
    #pragma unroll
    for (int e = 0; e < 8; ++e) z8[e] = (bf16_t)0.f;
    bf16x8 qf[4], kf[4];
    #pragma unroll
    for (int t = 0; t < 4; ++t) {
        const int n = t * 16 + lrow;
        const int nc = (n < 49) ? n : 48;
        bf16x8 qv = *(const bf16x8*)(base + (long)nc * 576 + lkg * 8);
        bf16x8 kv = *(const bf16x8*)(base + (long)nc * 576 + 192 + lkg * 8);
        qf[t] = (n < 49) ? qv : z8;
        kf[t] = (n < 49) ? kv : z8;
    }
    f32x4 zf; zf[0] = zf[1] = zf[2] = zf[3] = 0.f;
    f32x4 S[4][4];
    #pragma unroll
    for (int mi = 0; mi < 4; ++mi)
        #pragma unroll
        for (int mj = 0; mj < 4; ++mj)
            S[mi][mj] = MFMA16(qf[mi], kf[mj], zf);

    // row softmax (cols >= 49 masked), P -> LDS as bf16
    const float scl = 0.17677669529663687f;   // 32^-0.5
    #pragma unroll
    for (int mi = 0; mi < 4; ++mi) {
        #pragma unroll
        for (int rg = 0; rg < 4; ++rg) {
            float v0 = S[mi][0][rg] * scl;
            float v1 = S[mi][1][rg] * scl;
            float v2 = S[mi][2][rg] * scl;
            float v3 = (lrow == 0) ? S[mi][3][rg] * scl : -1e30f;  // col 48+lrow
            float mx = fmaxf(fmaxf(v0, v1), fmaxf(v2, v3));
            #pragma unroll
            for (int d = 1; d < 16; d <<= 1) mx = fmaxf(mx, __shfl_xor(mx, d));
            float e0 = expf(v0 - mx), e1 = expf(v1 - mx), e2 = expf(v2 - mx);
            float e3 = (lrow == 0) ? expf(v3 - mx) : 0.f;
            float sm = e0 + e1 + e2 + e3;
            #pragma unroll
            for (int d = 1; d < 16; d <<= 1) sm += __shfl_xor(sm, d);
            float is = 1.f / sm;
            const int row = mi * 16 + lkg * 4 + rg;
            Pl[row][lrow]      = (bf16_t)(e0 * is);
            Pl[row][16 + lrow] = (bf16_t)(e1 * is);
            Pl[row][32 + lrow] = (bf16_t)(e2 * is);
            Pl[row][48 + lrow] = (bf16_t)(e3 * is);
        }
    }
    __syncthreads();

    // PV: out[n][d] = sum_m P[n][m] Vt[d][m]
    f32x4 o[4][2];
    #pragma unroll
    for (int ni = 0; ni < 4; ++ni)
        #pragma unroll
        for (int di = 0; di < 2; ++di)
            #pragma unroll
            for (int rg = 0; rg < 4; ++rg) o[ni][di][rg] = 0.f;
    #pragma unroll
    for (int m0 = 0; m0 < 64; m0 += 32) {
        bf16x8 pf[4], vf[2];
        #pragma unroll
        for (int ni = 0; ni < 4; ++ni)
            pf[ni] = *(const bf16x8*)(&Pl[ni * 16 + lrow][m0 + lkg * 8]);
        #pragma unroll
        for (int di = 0; di < 2; ++di)
            vf[di] = *(const bf16x8*)(&Vt[di * 16 + lrow][m0 + lkg * 8]);
        #pragma unroll
        for (int ni = 0; ni < 4; ++ni)
            #pragma unroll
            for (int di = 0; di < 2; ++di)
                o[ni][di] = MFMA16(pf[ni], vf[di], o[ni][di]);
    }
    #pragma unroll
    for (int ni = 0; ni < 4; ++ni) {
        #pragma unroll
        for (int rg = 0; rg < 4; ++rg) {
            const int n = ni * 16 + lkg * 4 + rg;
            if (n < 49) {
                bf16_t* orow = aout + ((long)win * 49 + n) * 192 + head * 32;
                orow[lrow]      = (bf16_t)o[ni][0][rg];
                orow[16 + lrow] = (bf16_t)o[ni][1][rg];
            }
        }
    }
}

// ---------------- final: un-window + roll(+3) + BHWC->BCHW + shortcut ----
__global__ __launch_bounds__(1024) void k_final(const bf16_t* __restrict__ fb,
                                                const float* __restrict__ x,
                                                float* __restrict__ out)
{
    __shared__ float tile[56][199];   // odd-ish stride: conflict-free col reads
    const int bh = blockIdx.x;
    const int b = bh / 56, hq = bh % 56;
    const int tid = threadIdx.x;
    const int hr = (hq + 53) % 56;
    const int nh = hr / 7, ii = hr % 7;
    const long rband = ((long)b * 64 + (long)nh * 8) * 49 + (long)ii * 7;

    // phase 1: gather fb rows (contiguous 384B/row) into tile[wq][c]
    for (int q = tid; q < 1344; q += 1024) {
        const int g = q / 168, rem = q % 168;
        const int jj = rem / 24, ci = rem % 24;
        const long rr = rband + (long)g * 49 + jj;
        bf16x8 v = *(const bf16x8*)(fb + rr * 192 + ci * 8);
        const int wq = (g * 7 + jj + 3) % 56;
        #pragma unroll
        for (int e = 0; e < 8; ++e) tile[wq][ci * 8 + e] = (float)v[e];
    }
    __syncthreads();

    // phase 2: out[b][c][hq][w] = tile[w][c] + x[b][c][hq][w]  (float4 along w)
    const int g = tid >> 4, u = tid & 15;
    if (u < 14) {
        #pragma unroll
        for (int k = 0; k < 3; ++k) {
            const int c = g + 64 * k;
            const long base = ((long)b * 192 + c) * 3136 + (long)hq * 56 + u * 4;
            float4 xv = *(const float4*)(x + base);
            float4 ov;
            ov.x = tile[u * 4 + 0][c] + xv.x;
            ov.y = tile[u * 4 + 1][c] + xv.y;
            ov.z = tile[u * 4 + 2][c] + xv.z;
            ov.w = tile[u * 4 + 3][c] + xv.w;
            *(float4*)(out + base) = ov;
        }
    }
}

extern "C" void kernel_launch(void* const* d_in, const int* in_sizes, int n_in,
                              void* d_out, int out_size, void* d_ws, size_t ws_size,
                              hipStream_t stream)
{
    const float* x     = (const float*)d_in[0];
    const float* n1w   = (const float*)d_in[1];
    const float* n1b   = (const float*)d_in[2];
    const float* qkvw  = (const float*)d_in[3];
    const float* qkvb  = (const float*)d_in[4];
    const float* projw = (const float*)d_in[5];
    const float* projb = (const float*)d_in[6];
    const float* n2w   = (const float*)d_in[7];
    const float* n2b   = (const float*)d_in[8];
    const float* fc1w  = (const float*)d_in[9];
    const float* fc1b  = (const float*)d_in[10];
    const float* fc2w  = (const float*)d_in[11];
    const float* fc2b  = (const float*)d_in[12];

    char* ws = (char*)d_ws;
    bf16_t* wqkv  = (bf16_t*)(ws);              // 576*192  bf16
    bf16_t* wproj = (bf16_t*)(ws + 221184);     // 192*192
    bf16_t* wfc1  = (bf16_t*)(ws + 294912);     // 768*192
    bf16_t* wfc2  = (bf16_t*)(ws + 589824);     // 192*768
    bf16_t* Xb    = (bf16_t*)(ws + 884736);     // [50176][192] bf16 (LN1 out, attn out)
    bf16_t* QKV   = (bf16_t*)(ws + 20152320);   // [50176][576] bf16
    bf16_t* Hb    = (bf16_t*)(ws + 77955072);   // [50176][768] bf16 (fc1 out)
    bf16_t* H2    = (bf16_t*)(ws + 155025408);  // [50176][192] bf16 (fc2 out)
    bf16_t* X2    = (bf16_t*)(ws + 174292992);  // [50176][192] bf16 (LN2 out)

    k_cvt<<<1728, 256, 0, stream>>>(qkvw, projw, fc1w, fc2w, wqkv);
    k_ln1<<<896, 1024, 0, stream>>>(x, n1w, n1b, Xb);
    k_gemm96<0, 576><<<dim3(6, 784), 256, 0, stream>>>(Xb, wqkv, qkvb, QKV);
    k_attn<<<dim3(1024, 6), 64, 0, stream>>>(QKV, Xb);
    k_proj_ln<<<784, 256, 0, stream>>>(Xb, wproj, projb, n2w, n2b, X2);
    k_gemm96<2, 768><<<dim3(8, 784), 256, 0, stream>>>(X2, wfc1, fc1b, Hb);
    k_gemm<0, 192, 768><<<dim3(392, 3), 256, 0, stream>>>(Hb, wfc2, fc2b, H2);
    k_final<<<896, 1024, 0, stream>>>(H2, x, (float*)d_out);
}